// Round 1
// baseline (2962.928 us; speedup 1.0000x reference)
//
#include <hip/hip_runtime.h>
#include <stdint.h>

// GMNConv restructured:
//  P = x@mW1[:128], Q = x@mW1[128:]+mb1   (node tables, bf16)
//  S[n] = sum_{e: tgt=n} relu(P[src]+Q[tgt])  (atomic scatter, fp32)
//  msg  = S@mW2 + deg*mb2
//  att  = block-diagonal cross attention (64 graphs x 128 nodes)
//  U    = [msg | att | x]  (bf16, [2N,512])
//  out  = x + relu(relu(U@uW1+b1)@uW2+b2)@uW3+b3

typedef unsigned short u16;
typedef __bf16 bf16x8 __attribute__((ext_vector_type(8)));
typedef float f32x4 __attribute__((ext_vector_type(4)));

#define NN 8192
#define DD 128
#define EE 131072
#define GS 128
#define NG 64

__device__ __forceinline__ float bf2f(u16 u){
  return __uint_as_float(((uint32_t)u) << 16);
}
__device__ __forceinline__ u16 f2bf(float f){
  uint32_t x = __float_as_uint(f);
  return (u16)((x + 0x7fffu + ((x >> 16) & 1u)) >> 16);
}

// ---- tiny weight transpose+cast: Wt[c*K+k] = W[(row0+k)*Nc + c] ----
__global__ void transpose_cast_k(const float* __restrict__ W, u16* __restrict__ Wt,
                                 int K, int Nc, int row0){
  int idx = blockIdx.x * 256 + threadIdx.x;
  if (idx >= K * Nc) return;
  int c = idx / K, k = idx - c * K;
  Wt[idx] = f2bf(W[(size_t)(row0 + k) * Nc + c]);
}

// ---- cast x to bf16 table + write x columns of U ----
__global__ void cast_x_k(const float* __restrict__ x, u16* __restrict__ xb,
                         u16* __restrict__ Uside){
  int idx = blockIdx.x * 256 + threadIdx.x;   // 0 .. NN*DD
  int n = idx >> 7, d = idx & 127;
  u16 v = f2bf(x[idx]);
  xb[idx] = v;
  Uside[(size_t)n * 512 + 384 + d] = v;
}

// ---- bf16 MFMA GEMM: C[M,Nc] = f(A[M,K] @ Wt^T + bias [+res]) ----
// Wt stored [Nc,K] row-major bf16. 64x64 tile, 256 thr, BK=32.
template<typename AT, bool RELU, bool DEGBIAS, bool RES, typename OT>
__global__ __launch_bounds__(256)
void gemm_k(const AT* __restrict__ A, int lda,
            const u16* __restrict__ Wt, const float* __restrict__ bias,
            const int* __restrict__ deg, const float* __restrict__ res,
            OT* __restrict__ out, int ldc, int K)
{
  __shared__ u16 As[64 * 40];   // stride 40 -> 2-way max bank alias on b128 reads
  __shared__ u16 Bs[64 * 40];
  const int t = threadIdx.x;
  const int brow = blockIdx.y << 6, bcol = blockIdx.x << 6;
  const int wave = t >> 6, lane = t & 63;
  const int rb = (wave >> 1) << 5, cb = (wave & 1) << 5;
  const int lr = lane & 15, lq = lane >> 4;
  const int srow = t >> 2, skc = (t & 3) << 3;

  f32x4 acc00 = {0.f, 0.f, 0.f, 0.f};
  f32x4 acc01 = acc00, acc10 = acc00, acc11 = acc00;

  for (int kb = 0; kb < K; kb += 32){
    if constexpr (sizeof(AT) == 2){
      *(uint4*)&As[srow * 40 + skc] =
          *(const uint4*)(A + (size_t)(brow + srow) * lda + kb + skc);
    } else {
      const float* ap = (const float*)A + (size_t)(brow + srow) * lda + kb + skc;
      float4 f0 = *(const float4*)ap;
      float4 f1 = *(const float4*)(ap + 4);
      uint4 pk;
      pk.x = (uint32_t)f2bf(f0.x) | ((uint32_t)f2bf(f0.y) << 16);
      pk.y = (uint32_t)f2bf(f0.z) | ((uint32_t)f2bf(f0.w) << 16);
      pk.z = (uint32_t)f2bf(f1.x) | ((uint32_t)f2bf(f1.y) << 16);
      pk.w = (uint32_t)f2bf(f1.z) | ((uint32_t)f2bf(f1.w) << 16);
      *(uint4*)&As[srow * 40 + skc] = pk;
    }
    *(uint4*)&Bs[srow * 40 + skc] =
        *(const uint4*)(Wt + (size_t)(bcol + srow) * K + kb + skc);
    __syncthreads();
    // A frag: row = lane&15, k = (lane>>4)*8 + j   (m89/m91-verified layout)
    bf16x8 a0 = *(const bf16x8*)&As[(rb + lr) * 40 + (lq << 3)];
    bf16x8 a1 = *(const bf16x8*)&As[(rb + 16 + lr) * 40 + (lq << 3)];
    bf16x8 b0 = *(const bf16x8*)&Bs[(cb + lr) * 40 + (lq << 3)];
    bf16x8 b1 = *(const bf16x8*)&Bs[(cb + 16 + lr) * 40 + (lq << 3)];
    acc00 = __builtin_amdgcn_mfma_f32_16x16x32_bf16(a0, b0, acc00, 0, 0, 0);
    acc01 = __builtin_amdgcn_mfma_f32_16x16x32_bf16(a0, b1, acc01, 0, 0, 0);
    acc10 = __builtin_amdgcn_mfma_f32_16x16x32_bf16(a1, b0, acc10, 0, 0, 0);
    acc11 = __builtin_amdgcn_mfma_f32_16x16x32_bf16(a1, b1, acc11, 0, 0, 0);
    __syncthreads();
  }

  f32x4 accs[2][2] = {{acc00, acc01}, {acc10, acc11}};
  #pragma unroll
  for (int mi = 0; mi < 2; mi++)
  #pragma unroll
  for (int ni = 0; ni < 2; ni++)
  #pragma unroll
  for (int r = 0; r < 4; r++){
    // C/D: col = lane&15, row = (lane>>4)*4 + r   (m89-verified)
    int grow = brow + rb + mi * 16 + lq * 4 + r;
    int gcol = bcol + cb + ni * 16 + lr;
    float v = accs[mi][ni][r];
    if (bias) v += DEGBIAS ? ((float)deg[grow]) * bias[gcol] : bias[gcol];
    if constexpr (RELU) v = fmaxf(v, 0.f);
    if constexpr (RES)  v += res[(size_t)grow * ldc + gcol];
    if constexpr (sizeof(OT) == 2) out[(size_t)grow * ldc + gcol] = (OT)f2bf(v);
    else                           out[(size_t)grow * ldc + gcol] = (OT)v;
  }
}

// ---- edge pass: S[tgt] += relu(P[src]+Q[tgt]), deg[tgt]++ ; 1 wave = 1 edge ----
__global__ __launch_bounds__(256)
void edge_k(const int* __restrict__ ei, const u16* __restrict__ P,
            const u16* __restrict__ Q, float* __restrict__ S,
            int* __restrict__ deg)
{
  const int wave = threadIdx.x >> 6, lane = threadIdx.x & 63;
  const int e = (blockIdx.x << 2) + wave;
  const int tgt = ei[e];
  const int src = ei[EE + e];
  if (lane == 0) atomicAdd(&deg[tgt], 1);
  const uint4 p = *(const uint4*)(P + (size_t)src * 512 + (lane << 3));
  const uint4 q = *(const uint4*)(Q + (size_t)tgt * 512 + (lane << 3));
  float* Sr = S + (size_t)tgt * 512 + (lane << 3);
  uint32_t pw[4] = {p.x, p.y, p.z, p.w};
  uint32_t qw[4] = {q.x, q.y, q.z, q.w};
  #pragma unroll
  for (int i = 0; i < 4; i++){
    float z0 = bf2f((u16)(pw[i] & 0xffffu)) + bf2f((u16)(qw[i] & 0xffffu));
    float z1 = bf2f((u16)(pw[i] >> 16))     + bf2f((u16)(qw[i] >> 16));
    if (z0 > 0.f) atomicAdd(Sr + (i << 1), z0);       // relu + skip-zero atomics
    if (z1 > 0.f) atomicAdd(Sr + (i << 1) + 1, z1);
  }
}

// ---- block-diagonal cross-attention: att = xA - softmax(xA@xBg^T)@xBg ----
// grid (64 graphs, 4 row-chunks), 256 thr, 2 rows at a time.
__global__ __launch_bounds__(256)
void attn_k(const float* __restrict__ xA, const float* __restrict__ xB,
            u16* __restrict__ Uside)
{
  __shared__ u16 xb[GS * 130];      // stride 130: (65j+w)%32 -> 2-way max
  __shared__ float xa[2][DD];
  __shared__ float sc[2][GS];
  __shared__ float red[2][2];
  const int g = blockIdx.x;
  const int t = threadIdx.x;
  const int hf = t >> 7, tt = t & 127, lane = t & 63;
  const float* xBg = xB + (size_t)g * GS * DD;
  for (int i = t; i < GS * DD; i += 256){
    int r = i >> 7, c = i & 127;
    xb[r * 130 + c] = f2bf(xBg[i]);
  }
  __syncthreads();
  const int r0 = blockIdx.y * 32;
  for (int i0 = r0; i0 < r0 + 32; i0 += 2){
    const int i = i0 + hf;
    xa[hf][tt] = xA[((size_t)g * GS + i) * DD + tt];
    __syncthreads();
    float s = 0.f;
    const u16* xr = &xb[tt * 130];
    #pragma unroll 8
    for (int d2 = 0; d2 < 64; d2++){
      uint32_t wv = *(const uint32_t*)&xr[d2 << 1];
      s += xa[hf][(d2 << 1)]     * bf2f((u16)(wv & 0xffffu));
      s += xa[hf][(d2 << 1) + 1] * bf2f((u16)(wv >> 16));
    }
    sc[hf][tt] = s;
    __syncthreads();
    if (tt < 64){
      float m = fmaxf(sc[hf][tt], sc[hf][tt + 64]);
      #pragma unroll
      for (int sh = 32; sh > 0; sh >>= 1) m = fmaxf(m, __shfl_down(m, sh, 64));
      if (lane == 0) red[hf][0] = m;
    }
    __syncthreads();
    float ev = __expf(sc[hf][tt] - red[hf][0]);
    sc[hf][tt] = ev;
    __syncthreads();
    if (tt < 64){
      float sm = sc[hf][tt] + sc[hf][tt + 64];
      #pragma unroll
      for (int sh = 32; sh > 0; sh >>= 1) sm += __shfl_down(sm, sh, 64);
      if (lane == 0) red[hf][1] = sm;
    }
    __syncthreads();
    const float inv = 1.f / red[hf][1];
    float o = 0.f;
    #pragma unroll 8
    for (int j = 0; j < GS; j++) o += sc[hf][j] * bf2f(xb[j * 130 + tt]);
    float att = xa[hf][tt] - o * inv;
    Uside[((size_t)g * GS + i) * 512 + 256 + tt] = f2bf(att);
    __syncthreads();
  }
}

extern "C" void kernel_launch(void* const* d_in, const int* in_sizes, int n_in,
                              void* d_out, int out_size, void* d_ws, size_t ws_size,
                              hipStream_t stream)
{
  const float* x1  = (const float*)d_in[0];
  const int*   ei1 = (const int*)  d_in[1];
  const float* x2  = (const float*)d_in[3];
  const int*   ei2 = (const int*)  d_in[4];
  const float* mW1 = (const float*)d_in[6];
  const float* mb1 = (const float*)d_in[7];
  const float* mW2 = (const float*)d_in[8];
  const float* mb2 = (const float*)d_in[9];
  const float* uW1 = (const float*)d_in[10];
  const float* ub1 = (const float*)d_in[11];
  const float* uW2 = (const float*)d_in[12];
  const float* ub2 = (const float*)d_in[13];
  const float* uW3 = (const float*)d_in[14];
  const float* ub3 = (const float*)d_in[15];
  float* out = (float*)d_out;

  char* w = (char*)d_ws;
  auto alloc = [&](size_t b){ char* p = w; w += (b + 255) & ~(size_t)255; return p; };
  float* S1   = (float*)alloc((size_t)NN * 512 * 4);
  float* S2   = (float*)alloc((size_t)NN * 512 * 4);
  int*   deg1 = (int*)  alloc(NN * 4);
  int*   deg2 = (int*)  alloc(NN * 4);
  u16* P1  = (u16*)alloc((size_t)NN * 512 * 2);
  u16* Q1  = (u16*)alloc((size_t)NN * 512 * 2);
  u16* P2  = (u16*)alloc((size_t)NN * 512 * 2);
  u16* Q2  = (u16*)alloc((size_t)NN * 512 * 2);
  u16* xb1 = (u16*)alloc((size_t)NN * DD * 2);
  u16* xb2 = (u16*)alloc((size_t)NN * DD * 2);
  u16* U   = (u16*)alloc((size_t)2 * NN * 512 * 2);
  u16* H1  = (u16*)alloc((size_t)2 * NN * 512 * 2);
  u16* H2  = (u16*)alloc((size_t)2 * NN * 256 * 2);
  u16* WtP  = (u16*)alloc(512 * 128 * 2);
  u16* WtQ  = (u16*)alloc(512 * 128 * 2);
  u16* Wtm2 = (u16*)alloc(256 * 512 * 2);
  u16* Wtu1 = (u16*)alloc(512 * 512 * 2);
  u16* Wtu2 = (u16*)alloc(256 * 512 * 2);
  u16* Wtu3 = (u16*)alloc(128 * 256 * 2);

  // zero S1,S2,deg1,deg2 (contiguous, all sizes 256B-aligned)
  hipMemsetAsync(S1, 0, (size_t)NN * 512 * 4 * 2 + (size_t)NN * 4 * 2, stream);

  transpose_cast_k<<<256,  256, 0, stream>>>(mW1, WtP,  128, 512, 0);
  transpose_cast_k<<<256,  256, 0, stream>>>(mW1, WtQ,  128, 512, 128);
  transpose_cast_k<<<512,  256, 0, stream>>>(mW2, Wtm2, 512, 256, 0);
  transpose_cast_k<<<1024, 256, 0, stream>>>(uW1, Wtu1, 512, 512, 0);
  transpose_cast_k<<<512,  256, 0, stream>>>(uW2, Wtu2, 512, 256, 0);
  transpose_cast_k<<<128,  256, 0, stream>>>(uW3, Wtu3, 256, 128, 0);

  cast_x_k<<<4096, 256, 0, stream>>>(x1, xb1, U);
  cast_x_k<<<4096, 256, 0, stream>>>(x2, xb2, U + (size_t)NN * 512);

  dim3 gPQ(8, 128);
  gemm_k<u16,false,false,false,u16><<<gPQ,256,0,stream>>>(xb1,128, WtP, nullptr,nullptr,nullptr, P1, 512, 128);
  gemm_k<u16,false,false,false,u16><<<gPQ,256,0,stream>>>(xb1,128, WtQ, mb1,    nullptr,nullptr, Q1, 512, 128);
  gemm_k<u16,false,false,false,u16><<<gPQ,256,0,stream>>>(xb2,128, WtP, nullptr,nullptr,nullptr, P2, 512, 128);
  gemm_k<u16,false,false,false,u16><<<gPQ,256,0,stream>>>(xb2,128, WtQ, mb1,    nullptr,nullptr, Q2, 512, 128);

  edge_k<<<EE / 4, 256, 0, stream>>>(ei1, P1, Q1, S1, deg1);
  edge_k<<<EE / 4, 256, 0, stream>>>(ei2, P2, Q2, S2, deg2);

  dim3 gMsg(4, 128);
  gemm_k<float,false,true,false,u16><<<gMsg,256,0,stream>>>(S1,512, Wtm2, mb2, deg1, nullptr, U,                    512, 512);
  gemm_k<float,false,true,false,u16><<<gMsg,256,0,stream>>>(S2,512, Wtm2, mb2, deg2, nullptr, U + (size_t)NN * 512, 512, 512);

  attn_k<<<dim3(NG, 4), 256, 0, stream>>>(x1, x2, U);
  attn_k<<<dim3(NG, 4), 256, 0, stream>>>(x2, x1, U + (size_t)NN * 512);

  dim3 gH1(8, 256);
  gemm_k<u16,true,false,false,u16><<<gH1,256,0,stream>>>(U, 512, Wtu1, ub1, nullptr, nullptr, H1, 512, 512);
  dim3 gH2(4, 256);
  gemm_k<u16,true,false,false,u16><<<gH2,256,0,stream>>>(H1,512, Wtu2, ub2, nullptr, nullptr, H2, 256, 512);
  dim3 gO(2, 128);
  gemm_k<u16,false,false,true,float><<<gO,256,0,stream>>>(H2,                    256, Wtu3, ub3, nullptr, x1, out,                   128, 256);
  gemm_k<u16,false,false,true,float><<<gO,256,0,stream>>>(H2 + (size_t)NN * 256, 256, Wtu3, ub3, nullptr, x2, out + (size_t)NN * DD, 128, 256);
}

// Round 2
// 423.233 us; speedup vs baseline: 7.0007x; 7.0007x over previous
//
#include <hip/hip_runtime.h>
#include <stdint.h>

// GMNConv restructured:
//  P = x@mW1[:128], Q = x@mW1[128:]+mb1   (node tables, bf16)
//  counting-sort edges by tgt (hist -> scan -> scatter)
//  S[n] = sum_{e: tgt=n} relu(P[src]+Q[n])  (register accumulation, NO atomics)
//  msg  = S@mW2 + deg*mb2
//  att  = block-diagonal cross attention (64 graphs x 128 nodes)
//  U    = [msg | att | x]  (bf16, [2N,512])
//  out  = x + relu(relu(U@uW1+b1)@uW2+b2)@uW3+b3

typedef unsigned short u16;
typedef __bf16 bf16x8 __attribute__((ext_vector_type(8)));
typedef float f32x4 __attribute__((ext_vector_type(4)));

#define NN 8192
#define DD 128
#define EE 131072
#define GS 128
#define NG 64

__device__ __forceinline__ float bf2f(u16 u){
  return __uint_as_float(((uint32_t)u) << 16);
}
__device__ __forceinline__ u16 f2bf(float f){
  uint32_t x = __float_as_uint(f);
  return (u16)((x + 0x7fffu + ((x >> 16) & 1u)) >> 16);
}

// ---- tiny weight transpose+cast: Wt[c*K+k] = W[(row0+k)*Nc + c] ----
__global__ void transpose_cast_k(const float* __restrict__ W, u16* __restrict__ Wt,
                                 int K, int Nc, int row0){
  int idx = blockIdx.x * 256 + threadIdx.x;
  if (idx >= K * Nc) return;
  int c = idx / K, k = idx - c * K;
  Wt[idx] = f2bf(W[(size_t)(row0 + k) * Nc + c]);
}

// ---- cast x to bf16 table + write x columns of U ----
__global__ void cast_x_k(const float* __restrict__ x, u16* __restrict__ xb,
                         u16* __restrict__ Uside){
  int idx = blockIdx.x * 256 + threadIdx.x;   // 0 .. NN*DD
  int n = idx >> 7, d = idx & 127;
  u16 v = f2bf(x[idx]);
  xb[idx] = v;
  Uside[(size_t)n * 512 + 384 + d] = v;
}

// ---- bf16 MFMA GEMM: C[M,Nc] = f(A[M,K] @ Wt^T + bias [+res]) ----
// Wt stored [Nc,K] row-major bf16. 64x64 tile, 256 thr, BK=32.
template<typename AT, bool RELU, bool DEGBIAS, bool RES, typename OT>
__global__ __launch_bounds__(256)
void gemm_k(const AT* __restrict__ A, int lda,
            const u16* __restrict__ Wt, const float* __restrict__ bias,
            const int* __restrict__ deg, const float* __restrict__ res,
            OT* __restrict__ out, int ldc, int K)
{
  __shared__ u16 As[64 * 40];   // stride 40 -> 2-way max bank alias on b128 reads
  __shared__ u16 Bs[64 * 40];
  const int t = threadIdx.x;
  const int brow = blockIdx.y << 6, bcol = blockIdx.x << 6;
  const int wave = t >> 6, lane = t & 63;
  const int rb = (wave >> 1) << 5, cb = (wave & 1) << 5;
  const int lr = lane & 15, lq = lane >> 4;
  const int srow = t >> 2, skc = (t & 3) << 3;

  f32x4 acc00 = {0.f, 0.f, 0.f, 0.f};
  f32x4 acc01 = acc00, acc10 = acc00, acc11 = acc00;

  for (int kb = 0; kb < K; kb += 32){
    if constexpr (sizeof(AT) == 2){
      *(uint4*)&As[srow * 40 + skc] =
          *(const uint4*)(A + (size_t)(brow + srow) * lda + kb + skc);
    } else {
      const float* ap = (const float*)A + (size_t)(brow + srow) * lda + kb + skc;
      float4 f0 = *(const float4*)ap;
      float4 f1 = *(const float4*)(ap + 4);
      uint4 pk;
      pk.x = (uint32_t)f2bf(f0.x) | ((uint32_t)f2bf(f0.y) << 16);
      pk.y = (uint32_t)f2bf(f0.z) | ((uint32_t)f2bf(f0.w) << 16);
      pk.z = (uint32_t)f2bf(f1.x) | ((uint32_t)f2bf(f1.y) << 16);
      pk.w = (uint32_t)f2bf(f1.z) | ((uint32_t)f2bf(f1.w) << 16);
      *(uint4*)&As[srow * 40 + skc] = pk;
    }
    *(uint4*)&Bs[srow * 40 + skc] =
        *(const uint4*)(Wt + (size_t)(bcol + srow) * K + kb + skc);
    __syncthreads();
    // A frag: row = lane&15, k = (lane>>4)*8 + j   (m89/m91-verified layout)
    bf16x8 a0 = *(const bf16x8*)&As[(rb + lr) * 40 + (lq << 3)];
    bf16x8 a1 = *(const bf16x8*)&As[(rb + 16 + lr) * 40 + (lq << 3)];
    bf16x8 b0 = *(const bf16x8*)&Bs[(cb + lr) * 40 + (lq << 3)];
    bf16x8 b1 = *(const bf16x8*)&Bs[(cb + 16 + lr) * 40 + (lq << 3)];
    acc00 = __builtin_amdgcn_mfma_f32_16x16x32_bf16(a0, b0, acc00, 0, 0, 0);
    acc01 = __builtin_amdgcn_mfma_f32_16x16x32_bf16(a0, b1, acc01, 0, 0, 0);
    acc10 = __builtin_amdgcn_mfma_f32_16x16x32_bf16(a1, b0, acc10, 0, 0, 0);
    acc11 = __builtin_amdgcn_mfma_f32_16x16x32_bf16(a1, b1, acc11, 0, 0, 0);
    __syncthreads();
  }

  f32x4 accs[2][2] = {{acc00, acc01}, {acc10, acc11}};
  #pragma unroll
  for (int mi = 0; mi < 2; mi++)
  #pragma unroll
  for (int ni = 0; ni < 2; ni++)
  #pragma unroll
  for (int r = 0; r < 4; r++){
    // C/D: col = lane&15, row = (lane>>4)*4 + r   (m89-verified)
    int grow = brow + rb + mi * 16 + lq * 4 + r;
    int gcol = bcol + cb + ni * 16 + lr;
    float v = accs[mi][ni][r];
    if (bias) v += DEGBIAS ? ((float)deg[grow]) * bias[gcol] : bias[gcol];
    if constexpr (RELU) v = fmaxf(v, 0.f);
    if constexpr (RES)  v += res[(size_t)grow * ldc + gcol];
    if constexpr (sizeof(OT) == 2) out[(size_t)grow * ldc + gcol] = (OT)f2bf(v);
    else                           out[(size_t)grow * ldc + gcol] = (OT)v;
  }
}

// ---- edge histogram: deg[tgt]++ (both sides via blockIdx.y) ----
__global__ void hist_k(const int* __restrict__ ei1, int* __restrict__ deg1,
                       const int* __restrict__ ei2, int* __restrict__ deg2){
  const int* ei = blockIdx.y ? ei2 : ei1;
  int* deg      = blockIdx.y ? deg2 : deg1;
  int e = blockIdx.x * 256 + threadIdx.x;
  atomicAdd(&deg[ei[e]], 1);
}

// ---- exclusive prefix scan over NN=8192 ints; one block per side ----
__global__ __launch_bounds__(256)
void scan_k(const int* __restrict__ deg1, int* __restrict__ offs1, int* __restrict__ cur1,
            const int* __restrict__ deg2, int* __restrict__ offs2, int* __restrict__ cur2){
  const int* deg = blockIdx.x ? deg2 : deg1;
  int* offs      = blockIdx.x ? offs2 : offs1;
  int* cur       = blockIdx.x ? cur2  : cur1;
  __shared__ int part[256];
  const int t = threadIdx.x;
  const int base = t * 32;
  int loc[32];
  int s = 0;
  #pragma unroll
  for (int i = 0; i < 32; i++){ loc[i] = s; s += deg[base + i]; }
  part[t] = s;
  __syncthreads();
  for (int off = 1; off < 256; off <<= 1){
    int v = (t >= off) ? part[t - off] : 0;
    __syncthreads();
    part[t] += v;
    __syncthreads();
  }
  int pre = (t == 0) ? 0 : part[t - 1];
  #pragma unroll
  for (int i = 0; i < 32; i++){
    int o = pre + loc[i];
    offs[base + i] = o;
    cur[base + i]  = o;
  }
  if (t == 255) offs[NN] = part[255];
}

// ---- scatter sources into tgt-sorted order ----
__global__ void scatter_k(const int* __restrict__ ei1, int* __restrict__ cur1, int* __restrict__ srt1,
                          const int* __restrict__ ei2, int* __restrict__ cur2, int* __restrict__ srt2){
  const int* ei = blockIdx.y ? ei2 : ei1;
  int* cur      = blockIdx.y ? cur2 : cur1;
  int* srt      = blockIdx.y ? srt2 : srt1;
  int e = blockIdx.x * 256 + threadIdx.x;
  int tgt = ei[e], src = ei[EE + e];
  int p = atomicAdd(&cur[tgt], 1);
  srt[p] = src;
}

// ---- gather: S[n] = sum_{src in list(n)} relu(P[src]+Q[n]); 1 wave = 1 node ----
__global__ __launch_bounds__(256)
void gather_k(const int* __restrict__ offs1, const int* __restrict__ srt1,
              const u16* __restrict__ P1, const u16* __restrict__ Q1, float* __restrict__ S1,
              const int* __restrict__ offs2, const int* __restrict__ srt2,
              const u16* __restrict__ P2, const u16* __restrict__ Q2, float* __restrict__ S2)
{
  const int* offs = blockIdx.y ? offs2 : offs1;
  const int* srt  = blockIdx.y ? srt2  : srt1;
  const u16* P    = blockIdx.y ? P2 : P1;
  const u16* Q    = blockIdx.y ? Q2 : Q1;
  float* S        = blockIdx.y ? S2 : S1;

  const int node = (blockIdx.x << 2) + (threadIdx.x >> 6);
  const int lane = threadIdx.x & 63;
  const int beg = offs[node], end = offs[node + 1];

  uint4 qv = *(const uint4*)(Q + (size_t)node * 512 + (lane << 3));
  float q[8];
  {
    uint32_t qw[4] = {qv.x, qv.y, qv.z, qv.w};
    #pragma unroll
    for (int i = 0; i < 4; i++){
      q[i * 2]     = bf2f((u16)(qw[i] & 0xffffu));
      q[i * 2 + 1] = bf2f((u16)(qw[i] >> 16));
    }
  }
  float acc[8] = {0.f,0.f,0.f,0.f,0.f,0.f,0.f,0.f};

  int e = beg;
  for (; e + 1 < end; e += 2){
    int s0 = srt[e], s1 = srt[e + 1];
    uint4 pa = *(const uint4*)(P + (size_t)s0 * 512 + (lane << 3));
    uint4 pb = *(const uint4*)(P + (size_t)s1 * 512 + (lane << 3));
    uint32_t aw[4] = {pa.x, pa.y, pa.z, pa.w};
    uint32_t bw[4] = {pb.x, pb.y, pb.z, pb.w};
    #pragma unroll
    for (int i = 0; i < 4; i++){
      acc[i*2]   += fmaxf(bf2f((u16)(aw[i] & 0xffffu)) + q[i*2],   0.f);
      acc[i*2+1] += fmaxf(bf2f((u16)(aw[i] >> 16))     + q[i*2+1], 0.f);
      acc[i*2]   += fmaxf(bf2f((u16)(bw[i] & 0xffffu)) + q[i*2],   0.f);
      acc[i*2+1] += fmaxf(bf2f((u16)(bw[i] >> 16))     + q[i*2+1], 0.f);
    }
  }
  if (e < end){
    int s0 = srt[e];
    uint4 pa = *(const uint4*)(P + (size_t)s0 * 512 + (lane << 3));
    uint32_t aw[4] = {pa.x, pa.y, pa.z, pa.w};
    #pragma unroll
    for (int i = 0; i < 4; i++){
      acc[i*2]   += fmaxf(bf2f((u16)(aw[i] & 0xffffu)) + q[i*2],   0.f);
      acc[i*2+1] += fmaxf(bf2f((u16)(aw[i] >> 16))     + q[i*2+1], 0.f);
    }
  }
  float* Sr = S + (size_t)node * 512 + (lane << 3);
  *(float4*)Sr       = make_float4(acc[0], acc[1], acc[2], acc[3]);
  *(float4*)(Sr + 4) = make_float4(acc[4], acc[5], acc[6], acc[7]);
}

// ---- block-diagonal cross-attention: att = xA - softmax(xA@xBg^T)@xBg ----
// grid (64 graphs, 4 row-chunks), 256 thr, 2 rows at a time.
__global__ __launch_bounds__(256)
void attn_k(const float* __restrict__ xA, const float* __restrict__ xB,
            u16* __restrict__ Uside)
{
  __shared__ u16 xb[GS * 130];      // stride 130: (65j+w)%32 -> 2-way max
  __shared__ float xa[2][DD];
  __shared__ float sc[2][GS];
  __shared__ float red[2][2];
  const int g = blockIdx.x;
  const int t = threadIdx.x;
  const int hf = t >> 7, tt = t & 127, lane = t & 63;
  const float* xBg = xB + (size_t)g * GS * DD;
  for (int i = t; i < GS * DD; i += 256){
    int r = i >> 7, c = i & 127;
    xb[r * 130 + c] = f2bf(xBg[i]);
  }
  __syncthreads();
  const int r0 = blockIdx.y * 32;
  for (int i0 = r0; i0 < r0 + 32; i0 += 2){
    const int i = i0 + hf;
    xa[hf][tt] = xA[((size_t)g * GS + i) * DD + tt];
    __syncthreads();
    float s = 0.f;
    const u16* xr = &xb[tt * 130];
    #pragma unroll 8
    for (int d2 = 0; d2 < 64; d2++){
      uint32_t wv = *(const uint32_t*)&xr[d2 << 1];
      s += xa[hf][(d2 << 1)]     * bf2f((u16)(wv & 0xffffu));
      s += xa[hf][(d2 << 1) + 1] * bf2f((u16)(wv >> 16));
    }
    sc[hf][tt] = s;
    __syncthreads();
    if (tt < 64){
      float m = fmaxf(sc[hf][tt], sc[hf][tt + 64]);
      #pragma unroll
      for (int sh = 32; sh > 0; sh >>= 1) m = fmaxf(m, __shfl_down(m, sh, 64));
      if (lane == 0) red[hf][0] = m;
    }
    __syncthreads();
    float ev = __expf(sc[hf][tt] - red[hf][0]);
    sc[hf][tt] = ev;
    __syncthreads();
    if (tt < 64){
      float sm = sc[hf][tt] + sc[hf][tt + 64];
      #pragma unroll
      for (int sh = 32; sh > 0; sh >>= 1) sm += __shfl_down(sm, sh, 64);
      if (lane == 0) red[hf][1] = sm;
    }
    __syncthreads();
    const float inv = 1.f / red[hf][1];
    float o = 0.f;
    #pragma unroll 8
    for (int j = 0; j < GS; j++) o += sc[hf][j] * bf2f(xb[j * 130 + tt]);
    float att = xa[hf][tt] - o * inv;
    Uside[((size_t)g * GS + i) * 512 + 256 + tt] = f2bf(att);
    __syncthreads();
  }
}

extern "C" void kernel_launch(void* const* d_in, const int* in_sizes, int n_in,
                              void* d_out, int out_size, void* d_ws, size_t ws_size,
                              hipStream_t stream)
{
  const float* x1  = (const float*)d_in[0];
  const int*   ei1 = (const int*)  d_in[1];
  const float* x2  = (const float*)d_in[3];
  const int*   ei2 = (const int*)  d_in[4];
  const float* mW1 = (const float*)d_in[6];
  const float* mb1 = (const float*)d_in[7];
  const float* mW2 = (const float*)d_in[8];
  const float* mb2 = (const float*)d_in[9];
  const float* uW1 = (const float*)d_in[10];
  const float* ub1 = (const float*)d_in[11];
  const float* uW2 = (const float*)d_in[12];
  const float* ub2 = (const float*)d_in[13];
  const float* uW3 = (const float*)d_in[14];
  const float* ub3 = (const float*)d_in[15];
  float* out = (float*)d_out;

  char* w = (char*)d_ws;
  auto alloc = [&](size_t b){ char* p = w; w += (b + 255) & ~(size_t)255; return p; };
  float* S1   = (float*)alloc((size_t)NN * 512 * 4);
  float* S2   = (float*)alloc((size_t)NN * 512 * 4);
  int*   deg1 = (int*)  alloc(NN * 4);     // deg1,deg2 contiguous for one memset
  int*   deg2 = (int*)  alloc(NN * 4);
  int*   offs1 = (int*) alloc((NN + 1) * 4);
  int*   offs2 = (int*) alloc((NN + 1) * 4);
  int*   cur1  = (int*) alloc(NN * 4);
  int*   cur2  = (int*) alloc(NN * 4);
  int*   srt1  = (int*) alloc((size_t)EE * 4);
  int*   srt2  = (int*) alloc((size_t)EE * 4);
  u16* P1  = (u16*)alloc((size_t)NN * 512 * 2);
  u16* Q1  = (u16*)alloc((size_t)NN * 512 * 2);
  u16* P2  = (u16*)alloc((size_t)NN * 512 * 2);
  u16* Q2  = (u16*)alloc((size_t)NN * 512 * 2);
  u16* xb1 = (u16*)alloc((size_t)NN * DD * 2);
  u16* xb2 = (u16*)alloc((size_t)NN * DD * 2);
  u16* U   = (u16*)alloc((size_t)2 * NN * 512 * 2);
  u16* H1  = (u16*)alloc((size_t)2 * NN * 512 * 2);
  u16* H2  = (u16*)alloc((size_t)2 * NN * 256 * 2);
  u16* WtP  = (u16*)alloc(512 * 128 * 2);
  u16* WtQ  = (u16*)alloc(512 * 128 * 2);
  u16* Wtm2 = (u16*)alloc(256 * 512 * 2);
  u16* Wtu1 = (u16*)alloc(512 * 512 * 2);
  u16* Wtu2 = (u16*)alloc(256 * 512 * 2);
  u16* Wtu3 = (u16*)alloc(128 * 256 * 2);

  // zero deg1+deg2 (contiguous)
  hipMemsetAsync(deg1, 0, (size_t)NN * 4 * 2, stream);

  transpose_cast_k<<<256,  256, 0, stream>>>(mW1, WtP,  128, 512, 0);
  transpose_cast_k<<<256,  256, 0, stream>>>(mW1, WtQ,  128, 512, 128);
  transpose_cast_k<<<512,  256, 0, stream>>>(mW2, Wtm2, 512, 256, 0);
  transpose_cast_k<<<1024, 256, 0, stream>>>(uW1, Wtu1, 512, 512, 0);
  transpose_cast_k<<<512,  256, 0, stream>>>(uW2, Wtu2, 512, 256, 0);
  transpose_cast_k<<<128,  256, 0, stream>>>(uW3, Wtu3, 256, 128, 0);

  cast_x_k<<<4096, 256, 0, stream>>>(x1, xb1, U);
  cast_x_k<<<4096, 256, 0, stream>>>(x2, xb2, U + (size_t)NN * 512);

  // counting sort of edges by tgt
  hist_k<<<dim3(EE / 256, 2), 256, 0, stream>>>(ei1, deg1, ei2, deg2);
  scan_k<<<2, 256, 0, stream>>>(deg1, offs1, cur1, deg2, offs2, cur2);
  scatter_k<<<dim3(EE / 256, 2), 256, 0, stream>>>(ei1, cur1, srt1, ei2, cur2, srt2);

  dim3 gPQ(8, 128);
  gemm_k<u16,false,false,false,u16><<<gPQ,256,0,stream>>>(xb1,128, WtP, nullptr,nullptr,nullptr, P1, 512, 128);
  gemm_k<u16,false,false,false,u16><<<gPQ,256,0,stream>>>(xb1,128, WtQ, mb1,    nullptr,nullptr, Q1, 512, 128);
  gemm_k<u16,false,false,false,u16><<<gPQ,256,0,stream>>>(xb2,128, WtP, nullptr,nullptr,nullptr, P2, 512, 128);
  gemm_k<u16,false,false,false,u16><<<gPQ,256,0,stream>>>(xb2,128, WtQ, mb1,    nullptr,nullptr, Q2, 512, 128);

  // edge aggregation, no atomics
  gather_k<<<dim3(NN / 4, 2), 256, 0, stream>>>(offs1, srt1, P1, Q1, S1,
                                                offs2, srt2, P2, Q2, S2);

  dim3 gMsg(4, 128);
  gemm_k<float,false,true,false,u16><<<gMsg,256,0,stream>>>(S1,512, Wtm2, mb2, deg1, nullptr, U,                    512, 512);
  gemm_k<float,false,true,false,u16><<<gMsg,256,0,stream>>>(S2,512, Wtm2, mb2, deg2, nullptr, U + (size_t)NN * 512, 512, 512);

  attn_k<<<dim3(NG, 4), 256, 0, stream>>>(x1, x2, U);
  attn_k<<<dim3(NG, 4), 256, 0, stream>>>(x2, x1, U + (size_t)NN * 512);

  dim3 gH1(8, 256);
  gemm_k<u16,true,false,false,u16><<<gH1,256,0,stream>>>(U, 512, Wtu1, ub1, nullptr, nullptr, H1, 512, 512);
  dim3 gH2(4, 256);
  gemm_k<u16,true,false,false,u16><<<gH2,256,0,stream>>>(H1,512, Wtu2, ub2, nullptr, nullptr, H2, 256, 512);
  dim3 gO(2, 128);
  gemm_k<u16,false,false,true,float><<<gO,256,0,stream>>>(H2,                    256, Wtu3, ub3, nullptr, x1, out,                   128, 256);
  gemm_k<u16,false,false,true,float><<<gO,256,0,stream>>>(H2 + (size_t)NN * 256, 256, Wtu3, ub3, nullptr, x2, out + (size_t)NN * DD, 128, 256);
}

// Round 4
// 308.241 us; speedup vs baseline: 9.6124x; 1.3731x over previous
//
#include <hip/hip_runtime.h>
#include <stdint.h>

// GMNConv restructured (R4 = R3 + transpose_x_k staging bugfix):
//  WtPQ = [mW1_top ; mW1_bot]^T bf16, bPQ = [0 ; mb1]
//  PQ   = xb @ WtPQ^T + bPQ        (one 128x128-tile MFMA GEMM, M=16384, N=1024)
//  counting-sort edges by tgt; S[n] = sum relu(P[src]+Q[n])  (bf16, no atomics)
//  msg  = S@mW2 + deg*mb2          (into U cols 0..255)
//  att  = MFMA block-diag cross-attention (into U cols 256..383)
//  U cols 384..511 = x
//  out  = x + relu(relu(U@uW1+b1)@uW2+b2)@uW3+b3

typedef unsigned short u16;
typedef __bf16 bf16x8 __attribute__((ext_vector_type(8)));
typedef float f32x4 __attribute__((ext_vector_type(4)));

#define NN 8192
#define DD 128
#define EE 131072
#define GS 128
#define NG 64

__device__ __forceinline__ float bf2f(u16 u){
  return __uint_as_float(((uint32_t)u) << 16);
}
__device__ __forceinline__ u16 f2bf(float f){
  uint32_t x = __float_as_uint(f);
  return (u16)((x + 0x7fffu + ((x >> 16) & 1u)) >> 16);
}
__device__ __forceinline__ void gload16(const u16* g, u16* l){
  __builtin_amdgcn_global_load_lds(
      (const __attribute__((address_space(1))) uint32_t*)(uintptr_t)g,
      (__attribute__((address_space(3))) uint32_t*)(uintptr_t)l, 16, 0, 0);
}

// ---- weight prep: all transposes/casts in one dispatch (2692 blocks) ----
__global__ void prep_w_k(const float* __restrict__ mW1, const float* __restrict__ mb1,
                         const float* __restrict__ mW2, const float* __restrict__ uW1,
                         const float* __restrict__ uW2, const float* __restrict__ uW3,
                         u16* __restrict__ WtPQ, float* __restrict__ bPQ,
                         u16* __restrict__ Wtm2, u16* __restrict__ Wtu1,
                         u16* __restrict__ Wtu2, u16* __restrict__ Wtu3){
  int b = blockIdx.x, t = threadIdx.x;
  if (b < 512){                       // WtPQ [1024][128]
    int idx = b * 256 + t; int c = idx >> 7, k = idx & 127;
    int row = (c < 512) ? k : 128 + k;
    WtPQ[idx] = f2bf(mW1[(size_t)row * 512 + (c & 511)]);
  } else if (b < 1024){               // Wtm2 [256][512]
    int idx = (b - 512) * 256 + t; int c = idx >> 9, k = idx & 511;
    Wtm2[idx] = f2bf(mW2[(size_t)k * 256 + c]);
  } else if (b < 2048){               // Wtu1 [512][512]
    int idx = (b - 1024) * 256 + t; int c = idx >> 9, k = idx & 511;
    Wtu1[idx] = f2bf(uW1[(size_t)k * 512 + c]);
  } else if (b < 2560){               // Wtu2 [256][512]
    int idx = (b - 2048) * 256 + t; int c = idx >> 9, k = idx & 511;
    Wtu2[idx] = f2bf(uW2[(size_t)k * 256 + c]);
  } else if (b < 2688){               // Wtu3 [128][256]
    int idx = (b - 2560) * 256 + t; int c = idx >> 8, k = idx & 255;
    Wtu3[idx] = f2bf(uW3[(size_t)k * 128 + c]);
  } else {                            // bPQ [1024]
    int idx = (b - 2688) * 256 + t;
    bPQ[idx] = (idx < 512) ? 0.f : mb1[idx - 512];
  }
}

// ---- cast x to bf16 table + write x columns of U (both sides) ----
__global__ void cast_x_k(const float* __restrict__ x1, const float* __restrict__ x2,
                         u16* __restrict__ xb, u16* __restrict__ U){
  int side = blockIdx.y;
  const float* x = side ? x2 : x1;
  int idx = blockIdx.x * 256 + threadIdx.x;   // 0..NN*DD
  int n = idx >> 7, d = idx & 127;
  u16 v = f2bf(x[idx]);
  xb[(size_t)side * NN * DD + idx] = v;
  U[((size_t)side * NN + n) * 512 + 384 + d] = v;
}

// ---- transpose bf16 x tables: xt[side][d][n] = xb[side][n][d] ----
__global__ __launch_bounds__(256)
void transpose_x_k(const u16* __restrict__ xb, u16* __restrict__ xt){
  __shared__ u16 T[64 * 136];
  const int side = blockIdx.y;
  const u16* src = xb + (size_t)side * NN * DD;
  u16* dst = xt + (size_t)side * DD * NN;
  const int n0 = blockIdx.x * 64, t = threadIdx.x;
  #pragma unroll
  for (int i = 0; i < 4; i++){        // 1024 slots = 64 rows x 16 (R3 bug: was 2)
    int s = i * 256 + t; int r = s >> 4, c8 = (s & 15) << 3;
    *(uint4*)&T[r * 136 + c8] = *(const uint4*)(src + (size_t)(n0 + r) * DD + c8);
  }
  __syncthreads();
  #pragma unroll
  for (int i = 0; i < 8; i++){
    int s = i * 256 + t;                 // 0..2047
    int d = s >> 4, n4 = (s & 15) << 2;
    uint32_t a0 = T[(n4 + 0) * 136 + d];
    uint32_t a1 = T[(n4 + 1) * 136 + d];
    uint32_t a2 = T[(n4 + 2) * 136 + d];
    uint32_t a3 = T[(n4 + 3) * 136 + d];
    uint2 pk; pk.x = a0 | (a1 << 16); pk.y = a2 | (a3 << 16);
    *(uint2*)(dst + (size_t)d * NN + n0 + n4) = pk;
  }
}

// ---- m97-style 128x128 MFMA GEMM, BK=32, global_load_lds width-16 ----
template<bool RELU, bool DEGBIAS, bool RES, typename OT>
__global__ __launch_bounds__(256)
void gemm2_k(const u16* __restrict__ A, int lda,
             const u16* __restrict__ Wt, const float* __restrict__ bias,
             const int* __restrict__ deg,
             const float* __restrict__ res1, const float* __restrict__ res2,
             OT* __restrict__ out, int ldc, int K)
{
  __shared__ u16 As[128 * 32];
  __shared__ u16 Bs[128 * 32];
  const int t = threadIdx.x;
  const int brow = blockIdx.y << 7, bcol = blockIdx.x << 7;
  const int w = t >> 6, lane = t & 63;
  const int rb = (w >> 1) << 6, cb = (w & 1) << 6;
  const int lr = lane & 15, lq = lane >> 4;

  f32x4 acc[4][4];
  #pragma unroll
  for (int i = 0; i < 4; i++)
    #pragma unroll
    for (int j = 0; j < 4; j++) acc[i][j] = (f32x4){0.f, 0.f, 0.f, 0.f};

  // staging slots: slot s (16B) -> LDS offset s*16, covers (row=s>>2, kblk=s&3)
  const int s0 = t, s1 = t + 256;
  const u16* Ag0 = A  + (size_t)(brow + (s0 >> 2)) * lda + ((s0 & 3) << 3);
  const u16* Ag1 = A  + (size_t)(brow + (s1 >> 2)) * lda + ((s1 & 3) << 3);
  const u16* Bg0 = Wt + (size_t)(bcol + (s0 >> 2)) * K   + ((s0 & 3) << 3);
  const u16* Bg1 = Wt + (size_t)(bcol + (s1 >> 2)) * K   + ((s1 & 3) << 3);
  u16* Al0 = &As[s0 * 8]; u16* Al1 = &As[s1 * 8];
  u16* Bl0 = &Bs[s0 * 8]; u16* Bl1 = &Bs[s1 * 8];

  for (int kb = 0; kb < K; kb += 32){
    gload16(Ag0 + kb, Al0);
    gload16(Ag1 + kb, Al1);
    gload16(Bg0 + kb, Bl0);
    gload16(Bg1 + kb, Bl1);
    __syncthreads();                    // drains vmcnt -> LDS valid
    bf16x8 af[4], bfr[4];
    #pragma unroll
    for (int mi = 0; mi < 4; mi++)
      af[mi] = *(const bf16x8*)&As[(rb + mi * 16 + lr) * 32 + (lq << 3)];
    #pragma unroll
    for (int ni = 0; ni < 4; ni++)
      bfr[ni] = *(const bf16x8*)&Bs[(cb + ni * 16 + lr) * 32 + (lq << 3)];
    #pragma unroll
    for (int mi = 0; mi < 4; mi++)
      #pragma unroll
      for (int ni = 0; ni < 4; ni++)
        acc[mi][ni] = __builtin_amdgcn_mfma_f32_16x16x32_bf16(af[mi], bfr[ni], acc[mi][ni], 0, 0, 0);
    __syncthreads();                    // protect LDS before next stage
  }

  #pragma unroll
  for (int mi = 0; mi < 4; mi++)
    #pragma unroll
    for (int ni = 0; ni < 4; ni++)
      #pragma unroll
      for (int rr = 0; rr < 4; rr++){
        int grow = brow + rb + mi * 16 + lq * 4 + rr;
        int gcol = bcol + cb + ni * 16 + lr;
        float v = acc[mi][ni][rr];
        if (bias) v += DEGBIAS ? (float)deg[grow] * bias[gcol] : bias[gcol];
        if constexpr (RELU) v = fmaxf(v, 0.f);
        if constexpr (RES){
          const float* rp = (grow < NN) ? res1 : res2;
          v += rp[(size_t)(grow & (NN - 1)) * ldc + gcol];
        }
        if constexpr (sizeof(OT) == 2) out[(size_t)grow * ldc + gcol] = (OT)f2bf(v);
        else                           out[(size_t)grow * ldc + gcol] = (OT)v;
      }
}

// ---- edge histogram: deg[side][tgt]++ ----
__global__ void hist_k(const int* __restrict__ ei1, const int* __restrict__ ei2,
                       int* __restrict__ deg){
  const int* ei = blockIdx.y ? ei2 : ei1;
  int* d = deg + blockIdx.y * NN;
  int e = blockIdx.x * 256 + threadIdx.x;
  atomicAdd(&d[ei[e]], 1);
}

// ---- exclusive prefix scan over NN=8192 ints; one block per side ----
__global__ __launch_bounds__(256)
void scan_k(const int* __restrict__ deg,
            int* __restrict__ offs1, int* __restrict__ cur1,
            int* __restrict__ offs2, int* __restrict__ cur2){
  const int* d = deg + blockIdx.x * NN;
  int* offs = blockIdx.x ? offs2 : offs1;
  int* cur  = blockIdx.x ? cur2  : cur1;
  __shared__ int part[256];
  const int t = threadIdx.x;
  const int base = t * 32;
  int loc[32];
  int s = 0;
  #pragma unroll
  for (int i = 0; i < 32; i++){ loc[i] = s; s += d[base + i]; }
  part[t] = s;
  __syncthreads();
  for (int off = 1; off < 256; off <<= 1){
    int v = (t >= off) ? part[t - off] : 0;
    __syncthreads();
    part[t] += v;
    __syncthreads();
  }
  int pre = (t == 0) ? 0 : part[t - 1];
  #pragma unroll
  for (int i = 0; i < 32; i++){
    int o = pre + loc[i];
    offs[base + i] = o;
    cur[base + i]  = o;
  }
  if (t == 255) offs[NN] = part[255];
}

// ---- scatter sources into tgt-sorted order ----
__global__ void scatter_k(const int* __restrict__ ei1, int* __restrict__ cur1, int* __restrict__ srt1,
                          const int* __restrict__ ei2, int* __restrict__ cur2, int* __restrict__ srt2){
  const int* ei = blockIdx.y ? ei2 : ei1;
  int* cur      = blockIdx.y ? cur2 : cur1;
  int* srt      = blockIdx.y ? srt2 : srt1;
  int e = blockIdx.x * 256 + threadIdx.x;
  int tgt = ei[e], src = ei[EE + e];
  int p = atomicAdd(&cur[tgt], 1);
  srt[p] = src;
}

// ---- gather: S[n] = sum_{src} relu(P[src]+Q[n]); 1 wave = 1 node; bf16 out ----
__global__ __launch_bounds__(256)
void gather_k(const int* __restrict__ offs1, const int* __restrict__ srt1,
              const int* __restrict__ offs2, const int* __restrict__ srt2,
              const u16* __restrict__ PQ, u16* __restrict__ S)
{
  const int side = blockIdx.y;
  const int* offs = side ? offs2 : offs1;
  const int* srt  = side ? srt2  : srt1;
  const u16* base = PQ + (size_t)side * NN * 1024;
  u16* Sb = S + (size_t)side * NN * 512;

  const int node = (blockIdx.x << 2) + (threadIdx.x >> 6);
  const int lane = threadIdx.x & 63;
  const int beg = offs[node], end = offs[node + 1];

  uint4 qv = *(const uint4*)(base + (size_t)node * 1024 + 512 + (lane << 3));
  float q[8];
  {
    uint32_t qw[4] = {qv.x, qv.y, qv.z, qv.w};
    #pragma unroll
    for (int i = 0; i < 4; i++){
      q[i * 2]     = bf2f((u16)(qw[i] & 0xffffu));
      q[i * 2 + 1] = bf2f((u16)(qw[i] >> 16));
    }
  }
  float acc[8] = {0.f,0.f,0.f,0.f,0.f,0.f,0.f,0.f};

  int e = beg;
  for (; e + 1 < end; e += 2){
    int s0 = srt[e], s1 = srt[e + 1];
    uint4 pa = *(const uint4*)(base + (size_t)s0 * 1024 + (lane << 3));
    uint4 pb = *(const uint4*)(base + (size_t)s1 * 1024 + (lane << 3));
    uint32_t aw[4] = {pa.x, pa.y, pa.z, pa.w};
    uint32_t bw[4] = {pb.x, pb.y, pb.z, pb.w};
    #pragma unroll
    for (int i = 0; i < 4; i++){
      acc[i*2]   += fmaxf(bf2f((u16)(aw[i] & 0xffffu)) + q[i*2],   0.f);
      acc[i*2+1] += fmaxf(bf2f((u16)(aw[i] >> 16))     + q[i*2+1], 0.f);
      acc[i*2]   += fmaxf(bf2f((u16)(bw[i] & 0xffffu)) + q[i*2],   0.f);
      acc[i*2+1] += fmaxf(bf2f((u16)(bw[i] >> 16))     + q[i*2+1], 0.f);
    }
  }
  if (e < end){
    int s0 = srt[e];
    uint4 pa = *(const uint4*)(base + (size_t)s0 * 1024 + (lane << 3));
    uint32_t aw[4] = {pa.x, pa.y, pa.z, pa.w};
    #pragma unroll
    for (int i = 0; i < 4; i++){
      acc[i*2]   += fmaxf(bf2f((u16)(aw[i] & 0xffffu)) + q[i*2],   0.f);
      acc[i*2+1] += fmaxf(bf2f((u16)(aw[i] >> 16))     + q[i*2+1], 0.f);
    }
  }
  uint4 pk;
  pk.x = (uint32_t)f2bf(acc[0]) | ((uint32_t)f2bf(acc[1]) << 16);
  pk.y = (uint32_t)f2bf(acc[2]) | ((uint32_t)f2bf(acc[3]) << 16);
  pk.z = (uint32_t)f2bf(acc[4]) | ((uint32_t)f2bf(acc[5]) << 16);
  pk.w = (uint32_t)f2bf(acc[6]) | ((uint32_t)f2bf(acc[7]) << 16);
  *(uint4*)(Sb + (size_t)node * 512 + (lane << 3)) = pk;
}

// ---- MFMA block-diagonal cross-attention ----
// grid (64 graphs, 2 halves, 2 sides); block = 4 waves, wave w owns 16 rows.
// scores S = Xa@Xb^T (MFMA) -> register softmax -> P overlays XaS ->
// O = P@Xb with B-frags straight from global xt (transposed table).
__global__ __launch_bounds__(256)
void attn2_k(const u16* __restrict__ xb, const u16* __restrict__ xt,
             u16* __restrict__ U)
{
  const int side = blockIdx.z;
  const int g = blockIdx.x;
  const int h = blockIdx.y;
  const u16* Xa = xb + (size_t)side * NN * DD;
  const u16* Xb = xb + (size_t)(1 - side) * NN * DD;
  const u16* Xt = xt + (size_t)(1 - side) * DD * NN;   // [128][8192]
  u16* Uside = U + (size_t)side * NN * 512;

  __shared__ u16 XaS[64 * 136];    // Xa rows h*64.. ; overlaid by P after scores
  __shared__ u16 XbS[128 * 136];

  const int t = threadIdx.x, w = t >> 6, lane = t & 63;
  const int lr = lane & 15, lq = lane >> 4;

  {
    const u16* sa = Xa + ((size_t)g * GS + h * 64) * DD;
    #pragma unroll
    for (int i = 0; i < 4; i++){
      int s = i * 256 + t; int r = s >> 4, c8 = (s & 15) << 3;
      *(uint4*)&XaS[r * 136 + c8] = *(const uint4*)(sa + (size_t)r * DD + c8);
    }
    const u16* sb = Xb + (size_t)g * GS * DD;
    #pragma unroll
    for (int i = 0; i < 8; i++){
      int s = i * 256 + t; int r = s >> 4, c8 = (s & 15) << 3;
      *(uint4*)&XbS[r * 136 + c8] = *(const uint4*)(sb + (size_t)r * DD + c8);
    }
  }
  __syncthreads();

  // scores: rows w*16..+15 (A-frag row = lane&15), cols ct*16+lr
  f32x4 sc[8];
  #pragma unroll
  for (int ct = 0; ct < 8; ct++) sc[ct] = (f32x4){0.f, 0.f, 0.f, 0.f};
  #pragma unroll
  for (int kb = 0; kb < 4; kb++){
    bf16x8 a = *(const bf16x8*)&XaS[(w * 16 + lr) * 136 + kb * 32 + (lq << 3)];
    #pragma unroll
    for (int ct = 0; ct < 8; ct++){
      bf16x8 b = *(const bf16x8*)&XbS[(ct * 16 + lr) * 136 + kb * 32 + (lq << 3)];
      sc[ct] = __builtin_amdgcn_mfma_f32_16x16x32_bf16(a, b, sc[ct], 0, 0, 0);
    }
  }
  // softmax per row (C-layout: row = w*16 + lq*4 + rr, col = ct*16 + lr)
  float inv[4];
  #pragma unroll
  for (int rr = 0; rr < 4; rr++){
    float m = sc[0][rr];
    #pragma unroll
    for (int ct = 1; ct < 8; ct++) m = fmaxf(m, sc[ct][rr]);
    #pragma unroll
    for (int sh = 1; sh < 16; sh <<= 1) m = fmaxf(m, __shfl_xor(m, sh, 64));
    float s = 0.f;
    #pragma unroll
    for (int ct = 0; ct < 8; ct++){
      float e = __expf(sc[ct][rr] - m);
      sc[ct][rr] = e; s += e;
    }
    #pragma unroll
    for (int sh = 1; sh < 16; sh <<= 1) s += __shfl_xor(s, sh, 64);
    inv[rr] = 1.f / s;
  }
  // write normalized P over this wave's own 16 rows of XaS
  #pragma unroll
  for (int ct = 0; ct < 8; ct++)
    #pragma unroll
    for (int rr = 0; rr < 4; rr++)
      XaS[(w * 16 + lq * 4 + rr) * 136 + ct * 16 + lr] = f2bf(sc[ct][rr] * inv[rr]);
  __syncthreads();

  // PV: O = P @ Xb ; B-frag row d from global xt[d][g*128 + j]
  f32x4 o[8];
  #pragma unroll
  for (int ct = 0; ct < 8; ct++) o[ct] = (f32x4){0.f, 0.f, 0.f, 0.f};
  #pragma unroll
  for (int kb = 0; kb < 4; kb++){
    bf16x8 a = *(const bf16x8*)&XaS[(w * 16 + lr) * 136 + kb * 32 + (lq << 3)];
    #pragma unroll
    for (int ct = 0; ct < 8; ct++){
      bf16x8 b = *(const bf16x8*)(Xt + (size_t)(ct * 16 + lr) * NN + g * GS + kb * 32 + (lq << 3));
      o[ct] = __builtin_amdgcn_mfma_f32_16x16x32_bf16(a, b, o[ct], 0, 0, 0);
    }
  }
  // epilogue: att = xa - O (xa re-read from global, L1-hot)
  const u16* XaG = Xa + ((size_t)g * GS + h * 64) * DD;
  #pragma unroll
  for (int ct = 0; ct < 8; ct++)
    #pragma unroll
    for (int rr = 0; rr < 4; rr++){
      int row = w * 16 + lq * 4 + rr, col = ct * 16 + lr;
      float xa = bf2f(XaG[(size_t)row * DD + col]);
      Uside[((size_t)g * GS + h * 64 + row) * 512 + 256 + col] = f2bf(xa - o[ct][rr]);
    }
}

extern "C" void kernel_launch(void* const* d_in, const int* in_sizes, int n_in,
                              void* d_out, int out_size, void* d_ws, size_t ws_size,
                              hipStream_t stream)
{
  const float* x1  = (const float*)d_in[0];
  const int*   ei1 = (const int*)  d_in[1];
  const float* x2  = (const float*)d_in[3];
  const int*   ei2 = (const int*)  d_in[4];
  const float* mW1 = (const float*)d_in[6];
  const float* mb1 = (const float*)d_in[7];
  const float* mW2 = (const float*)d_in[8];
  const float* mb2 = (const float*)d_in[9];
  const float* uW1 = (const float*)d_in[10];
  const float* ub1 = (const float*)d_in[11];
  const float* uW2 = (const float*)d_in[12];
  const float* ub2 = (const float*)d_in[13];
  const float* uW3 = (const float*)d_in[14];
  const float* ub3 = (const float*)d_in[15];
  float* out = (float*)d_out;

  char* w = (char*)d_ws;
  auto alloc = [&](size_t b){ char* p = w; w += (b + 255) & ~(size_t)255; return p; };
  u16*  S    = (u16*)alloc((size_t)2 * NN * 512 * 2);
  u16*  PQ   = (u16*)alloc((size_t)2 * NN * 1024 * 2);
  u16*  xb   = (u16*)alloc((size_t)2 * NN * DD * 2);
  u16*  xt   = (u16*)alloc((size_t)2 * DD * NN * 2);
  u16*  U    = (u16*)alloc((size_t)2 * NN * 512 * 2);
  u16*  H1   = (u16*)alloc((size_t)2 * NN * 512 * 2);
  u16*  H2   = (u16*)alloc((size_t)2 * NN * 256 * 2);
  int*  deg  = (int*)alloc((size_t)2 * NN * 4);
  int*  offs1 = (int*)alloc((NN + 1) * 4);
  int*  offs2 = (int*)alloc((NN + 1) * 4);
  int*  cur1  = (int*)alloc(NN * 4);
  int*  cur2  = (int*)alloc(NN * 4);
  int*  srt1  = (int*)alloc((size_t)EE * 4);
  int*  srt2  = (int*)alloc((size_t)EE * 4);
  u16*  WtPQ = (u16*)alloc(1024 * 128 * 2);
  float* bPQ = (float*)alloc(1024 * 4);
  u16*  Wtm2 = (u16*)alloc(256 * 512 * 2);
  u16*  Wtu1 = (u16*)alloc(512 * 512 * 2);
  u16*  Wtu2 = (u16*)alloc(256 * 512 * 2);
  u16*  Wtu3 = (u16*)alloc(128 * 256 * 2);

  hipMemsetAsync(deg, 0, (size_t)2 * NN * 4, stream);

  prep_w_k<<<2692, 256, 0, stream>>>(mW1, mb1, mW2, uW1, uW2, uW3,
                                     WtPQ, bPQ, Wtm2, Wtu1, Wtu2, Wtu3);
  cast_x_k<<<dim3(4096, 2), 256, 0, stream>>>(x1, x2, xb, U);
  transpose_x_k<<<dim3(128, 2), 256, 0, stream>>>(xb, xt);

  // counting sort of edges by tgt
  hist_k<<<dim3(EE / 256, 2), 256, 0, stream>>>(ei1, ei2, deg);
  scan_k<<<2, 256, 0, stream>>>(deg, offs1, cur1, offs2, cur2);
  scatter_k<<<dim3(EE / 256, 2), 256, 0, stream>>>(ei1, cur1, srt1, ei2, cur2, srt2);

  // PQ = xb @ WtPQ^T + bPQ   (M=16384, N=1024, K=128)
  gemm2_k<false,false,false,u16><<<dim3(8,128),256,0,stream>>>(
      xb, 128, WtPQ, bPQ, nullptr, nullptr, nullptr, PQ, 1024, 128);

  // edge aggregation, no atomics
  gather_k<<<dim3(NN / 4, 2), 256, 0, stream>>>(offs1, srt1, offs2, srt2, PQ, S);

  // msg = S @ Wtm2^T + deg*mb2  (M=16384, N=256, K=512) -> U cols 0..255
  gemm2_k<false,true,false,u16><<<dim3(2,128),256,0,stream>>>(
      S, 512, Wtm2, mb2, deg, nullptr, nullptr, U, 512, 512);

  // cross-attention -> U cols 256..383
  attn2_k<<<dim3(NG, 2, 2), 256, 0, stream>>>(xb, xt, U);

  // update MLP
  gemm2_k<true,false,false,u16><<<dim3(4,128),256,0,stream>>>(
      U, 512, Wtu1, ub1, nullptr, nullptr, nullptr, H1, 512, 512);
  gemm2_k<true,false,false,u16><<<dim3(2,128),256,0,stream>>>(
      H1, 512, Wtu2, ub2, nullptr, nullptr, nullptr, H2, 256, 512);
  gemm2_k<false,false,true,float><<<dim3(1,128),256,0,stream>>>(
      H2, 256, Wtu3, ub3, nullptr, x1, x2, out, 128, 256);
}

// Round 5
// 283.639 us; speedup vs baseline: 10.4461x; 1.0867x over previous
//
#include <hip/hip_runtime.h>
#include <stdint.h>

// GMNConv R5 = R4 + dispatch fusion (14 -> 9 graph nodes) + gather unroll-4.
//  pre_k    : weight transpose/cast + x cast (+U x-cols) + edge histogram
//  scan_k   : exclusive prefix scan of deg -> offs/cur
//  mid_k    : PQ = xb@WtPQ^T + bPQ (MFMA)  ||  scatter edges  ||  transpose x
//  gather_k : S[n] = sum relu(P[src]+Q[n])   (no atomics)
//  msgattn_k: msg = S@mW2 + deg*mb2 (MFMA)  ||  block-diag cross-attention
//  gemm2_k  : H1 = relu(U@uW1+b1); H2 = relu(H1@uW2+b2); out = x + H2@uW3+b3

typedef unsigned short u16;
typedef __bf16 bf16x8 __attribute__((ext_vector_type(8)));
typedef float f32x4 __attribute__((ext_vector_type(4)));

#define NN 8192
#define DD 128
#define EE 131072
#define GS 128
#define NG 64

__device__ __forceinline__ float bf2f(u16 u){
  return __uint_as_float(((uint32_t)u) << 16);
}
__device__ __forceinline__ u16 f2bf(float f){
  uint32_t x = __float_as_uint(f);
  return (u16)((x + 0x7fffu + ((x >> 16) & 1u)) >> 16);
}
__device__ __forceinline__ void gload16(const u16* g, u16* l){
  __builtin_amdgcn_global_load_lds(
      (const __attribute__((address_space(1))) uint32_t*)(uintptr_t)g,
      (__attribute__((address_space(3))) uint32_t*)(uintptr_t)l, 16, 0, 0);
}

// ---- shared GEMM body: C[128x128 tile] = f(A@Wt^T + bias [+res]) ----
// Wt [Nc][K] row-major bf16; BK=32; global_load_lds width-16.
template<bool RELU, bool DEGBIAS, bool RES, typename OT>
__device__ __forceinline__ void gemm_body(
    const u16* __restrict__ A, int lda,
    const u16* __restrict__ Wt, const float* __restrict__ bias,
    const int* __restrict__ deg,
    const float* __restrict__ res1, const float* __restrict__ res2,
    OT* __restrict__ out, int ldc, int K, int bx, int by,
    u16* As, u16* Bs, int t)
{
  const int brow = by << 7, bcol = bx << 7;
  const int w = t >> 6, lane = t & 63;
  const int rb = (w >> 1) << 6, cb = (w & 1) << 6;
  const int lr = lane & 15, lq = lane >> 4;

  f32x4 acc[4][4];
  #pragma unroll
  for (int i = 0; i < 4; i++)
    #pragma unroll
    for (int j = 0; j < 4; j++) acc[i][j] = (f32x4){0.f, 0.f, 0.f, 0.f};

  const int s0 = t, s1 = t + 256;
  const u16* Ag0 = A  + (size_t)(brow + (s0 >> 2)) * lda + ((s0 & 3) << 3);
  const u16* Ag1 = A  + (size_t)(brow + (s1 >> 2)) * lda + ((s1 & 3) << 3);
  const u16* Bg0 = Wt + (size_t)(bcol + (s0 >> 2)) * K   + ((s0 & 3) << 3);
  const u16* Bg1 = Wt + (size_t)(bcol + (s1 >> 2)) * K   + ((s1 & 3) << 3);
  u16* Al0 = &As[s0 * 8]; u16* Al1 = &As[s1 * 8];
  u16* Bl0 = &Bs[s0 * 8]; u16* Bl1 = &Bs[s1 * 8];

  for (int kb = 0; kb < K; kb += 32){
    gload16(Ag0 + kb, Al0);
    gload16(Ag1 + kb, Al1);
    gload16(Bg0 + kb, Bl0);
    gload16(Bg1 + kb, Bl1);
    __syncthreads();
    bf16x8 af[4], bfr[4];
    #pragma unroll
    for (int mi = 0; mi < 4; mi++)
      af[mi] = *(const bf16x8*)&As[(rb + mi * 16 + lr) * 32 + (lq << 3)];
    #pragma unroll
    for (int ni = 0; ni < 4; ni++)
      bfr[ni] = *(const bf16x8*)&Bs[(cb + ni * 16 + lr) * 32 + (lq << 3)];
    #pragma unroll
    for (int mi = 0; mi < 4; mi++)
      #pragma unroll
      for (int ni = 0; ni < 4; ni++)
        acc[mi][ni] = __builtin_amdgcn_mfma_f32_16x16x32_bf16(af[mi], bfr[ni], acc[mi][ni], 0, 0, 0);
    __syncthreads();
  }

  #pragma unroll
  for (int mi = 0; mi < 4; mi++)
    #pragma unroll
    for (int ni = 0; ni < 4; ni++)
      #pragma unroll
      for (int rr = 0; rr < 4; rr++){
        int grow = brow + rb + mi * 16 + lq * 4 + rr;
        int gcol = bcol + cb + ni * 16 + lr;
        float v = acc[mi][ni][rr];
        if (bias) v += DEGBIAS ? (float)deg[grow] * bias[gcol] : bias[gcol];
        if constexpr (RELU) v = fmaxf(v, 0.f);
        if constexpr (RES){
          const float* rp = (grow < NN) ? res1 : res2;
          v += rp[(size_t)(grow & (NN - 1)) * ldc + gcol];
        }
        if constexpr (sizeof(OT) == 2) out[(size_t)grow * ldc + gcol] = (OT)f2bf(v);
        else                           out[(size_t)grow * ldc + gcol] = (OT)v;
      }
}

// ---- standalone GEMM kernel (H1 / H2 / out) ----
template<bool RELU, bool RES, typename OT>
__global__ __launch_bounds__(256)
void gemm2_k(const u16* __restrict__ A, int lda,
             const u16* __restrict__ Wt, const float* __restrict__ bias,
             const float* __restrict__ res1, const float* __restrict__ res2,
             OT* __restrict__ out, int ldc, int K)
{
  __shared__ u16 sh[8192];
  gemm_body<RELU,false,RES,OT>(A, lda, Wt, bias, nullptr, res1, res2,
                               out, ldc, K, blockIdx.x, blockIdx.y,
                               sh, sh + 4096, threadIdx.x);
}

// ---- pre_k: prep weights | cast x (+U x-cols) | edge histogram ----
__global__ __launch_bounds__(256)
void pre_k(const float* __restrict__ mW1, const float* __restrict__ mb1,
           const float* __restrict__ mW2, const float* __restrict__ uW1,
           const float* __restrict__ uW2, const float* __restrict__ uW3,
           const float* __restrict__ x1, const float* __restrict__ x2,
           const int* __restrict__ ei1, const int* __restrict__ ei2,
           u16* __restrict__ WtPQ, float* __restrict__ bPQ,
           u16* __restrict__ Wtm2, u16* __restrict__ Wtu1,
           u16* __restrict__ Wtu2, u16* __restrict__ Wtu3,
           u16* __restrict__ xb, u16* __restrict__ U,
           int* __restrict__ deg)
{
  int b = blockIdx.x, t = threadIdx.x;
  if (b < 2692){
    // weight prep
    if (b < 512){                       // WtPQ [1024][128]
      int idx = b * 256 + t; int c = idx >> 7, k = idx & 127;
      int row = (c < 512) ? k : 128 + k;
      WtPQ[idx] = f2bf(mW1[(size_t)row * 512 + (c & 511)]);
    } else if (b < 1024){               // Wtm2 [256][512]
      int idx = (b - 512) * 256 + t; int c = idx >> 9, k = idx & 511;
      Wtm2[idx] = f2bf(mW2[(size_t)k * 256 + c]);
    } else if (b < 2048){               // Wtu1 [512][512]
      int idx = (b - 1024) * 256 + t; int c = idx >> 9, k = idx & 511;
      Wtu1[idx] = f2bf(uW1[(size_t)k * 512 + c]);
    } else if (b < 2560){               // Wtu2 [256][512]
      int idx = (b - 2048) * 256 + t; int c = idx >> 9, k = idx & 511;
      Wtu2[idx] = f2bf(uW2[(size_t)k * 256 + c]);
    } else if (b < 2688){               // Wtu3 [128][256]
      int idx = (b - 2560) * 256 + t; int c = idx >> 8, k = idx & 255;
      Wtu3[idx] = f2bf(uW3[(size_t)k * 128 + c]);
    } else {                            // bPQ [1024]
      int idx = (b - 2688) * 256 + t;
      bPQ[idx] = (idx < 512) ? 0.f : mb1[idx - 512];
    }
  } else if (b < 2692 + 8192){
    // cast x -> xb + U x-columns
    int a = b - 2692;
    int side = a >> 12, blk = a & 4095;
    const float* x = side ? x2 : x1;
    int idx = blk * 256 + t;
    int n = idx >> 7, d = idx & 127;
    u16 v = f2bf(x[idx]);
    xb[(size_t)side * NN * DD + idx] = v;
    U[((size_t)side * NN + n) * 512 + 384 + d] = v;
  } else {
    // histogram
    int a = b - (2692 + 8192);
    int side = a >> 9, blk = a & 511;
    const int* ei = side ? ei2 : ei1;
    int e = blk * 256 + t;
    atomicAdd(&deg[side * NN + ei[e]], 1);
  }
}

// ---- exclusive prefix scan over NN=8192 ints; one block per side ----
__global__ __launch_bounds__(256)
void scan_k(const int* __restrict__ deg,
            int* __restrict__ offs1, int* __restrict__ cur1,
            int* __restrict__ offs2, int* __restrict__ cur2){
  const int* d = deg + blockIdx.x * NN;
  int* offs = blockIdx.x ? offs2 : offs1;
  int* cur  = blockIdx.x ? cur2  : cur1;
  __shared__ int part[256];
  const int t = threadIdx.x;
  const int base = t * 32;
  int loc[32];
  int s = 0;
  #pragma unroll
  for (int i = 0; i < 32; i++){ loc[i] = s; s += d[base + i]; }
  part[t] = s;
  __syncthreads();
  for (int off = 1; off < 256; off <<= 1){
    int v = (t >= off) ? part[t - off] : 0;
    __syncthreads();
    part[t] += v;
    __syncthreads();
  }
  int pre = (t == 0) ? 0 : part[t - 1];
  #pragma unroll
  for (int i = 0; i < 32; i++){
    int o = pre + loc[i];
    offs[base + i] = o;
    cur[base + i]  = o;
  }
  if (t == 255) offs[NN] = part[255];
}

// ---- mid_k: PQ GEMM | scatter edges | transpose x ----
__global__ __launch_bounds__(256)
void mid_k(const u16* __restrict__ xb, const u16* __restrict__ WtPQ,
           const float* __restrict__ bPQ, u16* __restrict__ PQ,
           const int* __restrict__ ei1, const int* __restrict__ ei2,
           int* __restrict__ cur1, int* __restrict__ cur2,
           int* __restrict__ srt1, int* __restrict__ srt2,
           u16* __restrict__ xt)
{
  __shared__ u16 sh[8704];
  const int b = blockIdx.x, t = threadIdx.x;
  if (b < 1024){
    // PQ = xb @ WtPQ^T + bPQ  (M=16384, N=1024, K=128); bx=b&7, by=b>>3
    gemm_body<false,false,false,u16>(xb, 128, WtPQ, bPQ, nullptr, nullptr, nullptr,
                                     PQ, 1024, 128, b & 7, b >> 3,
                                     sh, sh + 4096, t);
  } else if (b < 2048){
    // scatter
    int a = b - 1024;
    int side = a >> 9, blk = a & 511;
    const int* ei = side ? ei2 : ei1;
    int* cur = side ? cur2 : cur1;
    int* srt = side ? srt2 : srt1;
    int e = blk * 256 + t;
    int tgt = ei[e], src = ei[EE + e];
    int p = atomicAdd(&cur[tgt], 1);
    srt[p] = src;
  } else {
    // transpose: xt[side][d][n] = xb[side][n][d], 64-node tile
    int a = b - 2048;
    int side = a >> 7, blk = a & 127;
    const u16* src = xb + (size_t)side * NN * DD;
    u16* dst = xt + (size_t)side * DD * NN;
    const int n0 = blk * 64;
    u16* T = sh;                        // 64*136 = 8704
    #pragma unroll
    for (int i = 0; i < 4; i++){
      int s = i * 256 + t; int r = s >> 4, c8 = (s & 15) << 3;
      *(uint4*)&T[r * 136 + c8] = *(const uint4*)(src + (size_t)(n0 + r) * DD + c8);
    }
    __syncthreads();
    #pragma unroll
    for (int i = 0; i < 8; i++){
      int s = i * 256 + t;
      int d = s >> 4, n4 = (s & 15) << 2;
      uint32_t a0 = T[(n4 + 0) * 136 + d];
      uint32_t a1 = T[(n4 + 1) * 136 + d];
      uint32_t a2 = T[(n4 + 2) * 136 + d];
      uint32_t a3 = T[(n4 + 3) * 136 + d];
      uint2 pk; pk.x = a0 | (a1 << 16); pk.y = a2 | (a3 << 16);
      *(uint2*)(dst + (size_t)d * NN + n0 + n4) = pk;
    }
  }
}

// ---- gather: S[n] = sum relu(P[src]+Q[n]); 1 wave = 1 node; unroll 4 ----
__global__ __launch_bounds__(256)
void gather_k(const int* __restrict__ offs1, const int* __restrict__ srt1,
              const int* __restrict__ offs2, const int* __restrict__ srt2,
              const u16* __restrict__ PQ, u16* __restrict__ S)
{
  const int side = blockIdx.y;
  const int* offs = side ? offs2 : offs1;
  const int* srt  = side ? srt2  : srt1;
  const u16* base = PQ + (size_t)side * NN * 1024;
  u16* Sb = S + (size_t)side * NN * 512;

  const int node = (blockIdx.x << 2) + (threadIdx.x >> 6);
  const int lane = threadIdx.x & 63;
  const int beg = offs[node], end = offs[node + 1];

  uint4 qv = *(const uint4*)(base + (size_t)node * 1024 + 512 + (lane << 3));
  float q[8];
  {
    uint32_t qw[4] = {qv.x, qv.y, qv.z, qv.w};
    #pragma unroll
    for (int i = 0; i < 4; i++){
      q[i * 2]     = bf2f((u16)(qw[i] & 0xffffu));
      q[i * 2 + 1] = bf2f((u16)(qw[i] >> 16));
    }
  }
  float acc[8] = {0.f,0.f,0.f,0.f,0.f,0.f,0.f,0.f};

  int e = beg;
  for (; e + 3 < end; e += 4){
    int sA = srt[e], sB = srt[e+1], sC = srt[e+2], sD = srt[e+3];
    uint4 pA = *(const uint4*)(base + (size_t)sA * 1024 + (lane << 3));
    uint4 pB = *(const uint4*)(base + (size_t)sB * 1024 + (lane << 3));
    uint4 pC = *(const uint4*)(base + (size_t)sC * 1024 + (lane << 3));
    uint4 pD = *(const uint4*)(base + (size_t)sD * 1024 + (lane << 3));
    uint32_t aw[4] = {pA.x, pA.y, pA.z, pA.w};
    uint32_t bw[4] = {pB.x, pB.y, pB.z, pB.w};
    uint32_t cw[4] = {pC.x, pC.y, pC.z, pC.w};
    uint32_t dw[4] = {pD.x, pD.y, pD.z, pD.w};
    #pragma unroll
    for (int i = 0; i < 4; i++){
      acc[i*2]   += fmaxf(bf2f((u16)(aw[i] & 0xffffu)) + q[i*2],   0.f)
                  + fmaxf(bf2f((u16)(bw[i] & 0xffffu)) + q[i*2],   0.f)
                  + fmaxf(bf2f((u16)(cw[i] & 0xffffu)) + q[i*2],   0.f)
                  + fmaxf(bf2f((u16)(dw[i] & 0xffffu)) + q[i*2],   0.f);
      acc[i*2+1] += fmaxf(bf2f((u16)(aw[i] >> 16))     + q[i*2+1], 0.f)
                  + fmaxf(bf2f((u16)(bw[i] >> 16))     + q[i*2+1], 0.f)
                  + fmaxf(bf2f((u16)(cw[i] >> 16))     + q[i*2+1], 0.f)
                  + fmaxf(bf2f((u16)(dw[i] >> 16))     + q[i*2+1], 0.f);
    }
  }
  for (; e < end; e++){
    int sA = srt[e];
    uint4 pA = *(const uint4*)(base + (size_t)sA * 1024 + (lane << 3));
    uint32_t aw[4] = {pA.x, pA.y, pA.z, pA.w};
    #pragma unroll
    for (int i = 0; i < 4; i++){
      acc[i*2]   += fmaxf(bf2f((u16)(aw[i] & 0xffffu)) + q[i*2],   0.f);
      acc[i*2+1] += fmaxf(bf2f((u16)(aw[i] >> 16))     + q[i*2+1], 0.f);
    }
  }
  uint4 pk;
  pk.x = (uint32_t)f2bf(acc[0]) | ((uint32_t)f2bf(acc[1]) << 16);
  pk.y = (uint32_t)f2bf(acc[2]) | ((uint32_t)f2bf(acc[3]) << 16);
  pk.z = (uint32_t)f2bf(acc[4]) | ((uint32_t)f2bf(acc[5]) << 16);
  pk.w = (uint32_t)f2bf(acc[6]) | ((uint32_t)f2bf(acc[7]) << 16);
  *(uint4*)(Sb + (size_t)node * 512 + (lane << 3)) = pk;
}

// ---- msgattn_k: msg GEMM | MFMA block-diag cross-attention ----
__global__ __launch_bounds__(256)
void msgattn_k(const u16* __restrict__ S, const u16* __restrict__ Wtm2,
               const float* __restrict__ mb2, const int* __restrict__ deg,
               const u16* __restrict__ xb, const u16* __restrict__ xt,
               u16* __restrict__ U)
{
  __shared__ u16 sh[26112];   // attn: XaS 8704 + XbS 17408 ; gemm: 8192
  const int b = blockIdx.x, t = threadIdx.x;
  if (b < 256){
    // msg = S @ Wtm2^T + deg*mb2 -> U cols 0..255 ; bx=b&1, by=b>>1
    gemm_body<false,true,false,u16>(S, 512, Wtm2, mb2, deg, nullptr, nullptr,
                                    U, 512, 512, b & 1, b >> 1,
                                    sh, sh + 4096, t);
    return;
  }
  const int a = b - 256;
  const int side = a >> 7;
  const int g = a & 63, h = (a >> 6) & 1;
  const u16* Xa = xb + (size_t)side * NN * DD;
  const u16* Xb = xb + (size_t)(1 - side) * NN * DD;
  const u16* Xt = xt + (size_t)(1 - side) * DD * NN;
  u16* Uside = U + (size_t)side * NN * 512;

  u16* XaS = sh;            // 64*136
  u16* XbS = sh + 8704;     // 128*136

  const int w = t >> 6, lane = t & 63;
  const int lr = lane & 15, lq = lane >> 4;

  {
    const u16* sa = Xa + ((size_t)g * GS + h * 64) * DD;
    #pragma unroll
    for (int i = 0; i < 4; i++){
      int s = i * 256 + t; int r = s >> 4, c8 = (s & 15) << 3;
      *(uint4*)&XaS[r * 136 + c8] = *(const uint4*)(sa + (size_t)r * DD + c8);
    }
    const u16* sb = Xb + (size_t)g * GS * DD;
    #pragma unroll
    for (int i = 0; i < 8; i++){
      int s = i * 256 + t; int r = s >> 4, c8 = (s & 15) << 3;
      *(uint4*)&XbS[r * 136 + c8] = *(const uint4*)(sb + (size_t)r * DD + c8);
    }
  }
  __syncthreads();

  f32x4 sc[8];
  #pragma unroll
  for (int ct = 0; ct < 8; ct++) sc[ct] = (f32x4){0.f, 0.f, 0.f, 0.f};
  #pragma unroll
  for (int kb = 0; kb < 4; kb++){
    bf16x8 aa = *(const bf16x8*)&XaS[(w * 16 + lr) * 136 + kb * 32 + (lq << 3)];
    #pragma unroll
    for (int ct = 0; ct < 8; ct++){
      bf16x8 bb = *(const bf16x8*)&XbS[(ct * 16 + lr) * 136 + kb * 32 + (lq << 3)];
      sc[ct] = __builtin_amdgcn_mfma_f32_16x16x32_bf16(aa, bb, sc[ct], 0, 0, 0);
    }
  }
  float inv[4];
  #pragma unroll
  for (int rr = 0; rr < 4; rr++){
    float m = sc[0][rr];
    #pragma unroll
    for (int ct = 1; ct < 8; ct++) m = fmaxf(m, sc[ct][rr]);
    #pragma unroll
    for (int sh_ = 1; sh_ < 16; sh_ <<= 1) m = fmaxf(m, __shfl_xor(m, sh_, 64));
    float s = 0.f;
    #pragma unroll
    for (int ct = 0; ct < 8; ct++){
      float e = __expf(sc[ct][rr] - m);
      sc[ct][rr] = e; s += e;
    }
    #pragma unroll
    for (int sh_ = 1; sh_ < 16; sh_ <<= 1) s += __shfl_xor(s, sh_, 64);
    inv[rr] = 1.f / s;
  }
  #pragma unroll
  for (int ct = 0; ct < 8; ct++)
    #pragma unroll
    for (int rr = 0; rr < 4; rr++)
      XaS[(w * 16 + lq * 4 + rr) * 136 + ct * 16 + lr] = f2bf(sc[ct][rr] * inv[rr]);
  __syncthreads();

  f32x4 o[8];
  #pragma unroll
  for (int ct = 0; ct < 8; ct++) o[ct] = (f32x4){0.f, 0.f, 0.f, 0.f};
  #pragma unroll
  for (int kb = 0; kb < 4; kb++){
    bf16x8 aa = *(const bf16x8*)&XaS[(w * 16 + lr) * 136 + kb * 32 + (lq << 3)];
    #pragma unroll
    for (int ct = 0; ct < 8; ct++){
      bf16x8 bb = *(const bf16x8*)(Xt + (size_t)(ct * 16 + lr) * NN + g * GS + kb * 32 + (lq << 3));
      o[ct] = __builtin_amdgcn_mfma_f32_16x16x32_bf16(aa, bb, o[ct], 0, 0, 0);
    }
  }
  const u16* XaG = Xa + ((size_t)g * GS + h * 64) * DD;
  #pragma unroll
  for (int ct = 0; ct < 8; ct++)
    #pragma unroll
    for (int rr = 0; rr < 4; rr++){
      int row = w * 16 + lq * 4 + rr, col = ct * 16 + lr;
      float xa = bf2f(XaG[(size_t)row * DD + col]);
      Uside[((size_t)g * GS + h * 64 + row) * 512 + 256 + col] = f2bf(xa - o[ct][rr]);
    }
}

extern "C" void kernel_launch(void* const* d_in, const int* in_sizes, int n_in,
                              void* d_out, int out_size, void* d_ws, size_t ws_size,
                              hipStream_t stream)
{
  const float* x1  = (const float*)d_in[0];
  const int*   ei1 = (const int*)  d_in[1];
  const float* x2  = (const float*)d_in[3];
  const int*   ei2 = (const int*)  d_in[4];
  const float* mW1 = (const float*)d_in[6];
  const float* mb1 = (const float*)d_in[7];
  const float* mW2 = (const float*)d_in[8];
  const float* mb2 = (const float*)d_in[9];
  const float* uW1 = (const float*)d_in[10];
  const float* ub1 = (const float*)d_in[11];
  const float* uW2 = (const float*)d_in[12];
  const float* ub2 = (const float*)d_in[13];
  const float* uW3 = (const float*)d_in[14];
  const float* ub3 = (const float*)d_in[15];
  float* out = (float*)d_out;

  char* w = (char*)d_ws;
  auto alloc = [&](size_t b){ char* p = w; w += (b + 255) & ~(size_t)255; return p; };
  u16*  S    = (u16*)alloc((size_t)2 * NN * 512 * 2);
  u16*  PQ   = (u16*)alloc((size_t)2 * NN * 1024 * 2);
  u16*  xb   = (u16*)alloc((size_t)2 * NN * DD * 2);
  u16*  xt   = (u16*)alloc((size_t)2 * DD * NN * 2);
  u16*  U    = (u16*)alloc((size_t)2 * NN * 512 * 2);
  u16*  H1   = (u16*)alloc((size_t)2 * NN * 512 * 2);
  u16*  H2   = (u16*)alloc((size_t)2 * NN * 256 * 2);
  int*  deg  = (int*)alloc((size_t)2 * NN * 4);
  int*  offs1 = (int*)alloc((NN + 1) * 4);
  int*  offs2 = (int*)alloc((NN + 1) * 4);
  int*  cur1  = (int*)alloc(NN * 4);
  int*  cur2  = (int*)alloc(NN * 4);
  int*  srt1  = (int*)alloc((size_t)EE * 4);
  int*  srt2  = (int*)alloc((size_t)EE * 4);
  u16*  WtPQ = (u16*)alloc(1024 * 128 * 2);
  float* bPQ = (float*)alloc(1024 * 4);
  u16*  Wtm2 = (u16*)alloc(256 * 512 * 2);
  u16*  Wtu1 = (u16*)alloc(512 * 512 * 2);
  u16*  Wtu2 = (u16*)alloc(256 * 512 * 2);
  u16*  Wtu3 = (u16*)alloc(128 * 256 * 2);

  hipMemsetAsync(deg, 0, (size_t)2 * NN * 4, stream);

  pre_k<<<2692 + 8192 + 1024, 256, 0, stream>>>(
      mW1, mb1, mW2, uW1, uW2, uW3, x1, x2, ei1, ei2,
      WtPQ, bPQ, Wtm2, Wtu1, Wtu2, Wtu3, xb, U, deg);

  scan_k<<<2, 256, 0, stream>>>(deg, offs1, cur1, offs2, cur2);

  mid_k<<<2304, 256, 0, stream>>>(xb, WtPQ, bPQ, PQ, ei1, ei2,
                                  cur1, cur2, srt1, srt2, xt);

  gather_k<<<dim3(NN / 4, 2), 256, 0, stream>>>(offs1, srt1, offs2, srt2, PQ, S);

  msgattn_k<<<512, 256, 0, stream>>>(S, Wtm2, mb2, deg, xb, xt, U);

  gemm2_k<true,false,u16><<<dim3(4,128),256,0,stream>>>(
      U, 512, Wtu1, ub1, nullptr, nullptr, H1, 512, 512);
  gemm2_k<true,false,u16><<<dim3(2,128),256,0,stream>>>(
      H1, 512, Wtu2, ub2, nullptr, nullptr, H2, 256, 512);
  gemm2_k<false,true,float><<<dim3(1,128),256,0,stream>>>(
      H2, 256, Wtu3, ub3, x1, x2, out, 128, 256);
}